// Round 1
// 1399.261 us; speedup vs baseline: 1.1041x; 1.1041x over previous
//
#include <hip/hip_runtime.h>

#define DTC 0.01f
#define LAM  2.88539008178f     // 2/ln2
#define L2E  1.44269504089f     // 1/ln2

typedef __attribute__((ext_vector_type(8))) short short8;
typedef __attribute__((ext_vector_type(4))) float floatx4;

#if __has_builtin(__builtin_amdgcn_exp2f)
#define EXP2F(x) __builtin_amdgcn_exp2f(x)
#else
#define EXP2F(x) exp2f(x)
#endif
#if __has_builtin(__builtin_amdgcn_rcpf)
#define RCPF(x) __builtin_amdgcn_rcpf(x)
#else
#define RCPF(x) (1.0f / (x))
#endif

__device__ __forceinline__ unsigned short f2bf(float f) {
    unsigned u = __float_as_uint(f);
    u += 0x7FFFu + ((u >> 16) & 1u);
    return (unsigned short)(u >> 16);
}
// 1/(1+2^y): with gate pre-activations pre-scaled by -1/ln2 this IS sigmoid;
// with +2/ln2 scaling, tanh = 1 - 2*rcp1p.
__device__ __forceinline__ float rcp1p(float y) {
    return RCPF(1.0f + EXP2F(y));
}
// Raw barrier: lgkmcnt(0) drains our LDS ops for cross-wave visibility, but
// deliberately does NOT drain vmcnt -> wave0's out/res global stores stay
// in flight across barriers instead of stalling every step.
__device__ __forceinline__ void wg_barrier() {
    asm volatile("s_waitcnt lgkmcnt(0)" ::: "memory");
    __builtin_amdgcn_s_barrier();
}

// LDS stride in bf16 elements; byte stride 272 = 16*17 (odd multiple of 16)
// spreads the b128 A-frag reads across bank groups.
#define U1S 136

#define MFMA(a, b, c) __builtin_amdgcn_mfma_f32_16x16x32_bf16((a), (b), (c), 0, 0, 0)

__global__ __launch_bounds__(256, 1) void lstm_mfma(
    const float* __restrict__ x,    const float* __restrict__ s0,
    const float* __restrict__ W_ih0,const float* __restrict__ W_hh0,
    const float* __restrict__ b_ih0,const float* __restrict__ b_hh0,
    const float* __restrict__ W_ih1,const float* __restrict__ W_hh1,
    const float* __restrict__ b_ih1,const float* __restrict__ b_hh1,
    const float* __restrict__ fc_W, const float* __restrict__ fc_b,
    const int* __restrict__ nsp,    float* __restrict__ out, int B)
{
    // U1: [16 rows m][cols: 0..63 = h_a(t) bf16, 64..127 = h_b(t) bf16]
    __shared__ __align__(16) unsigned short U1[16 * U1S];

    const int ns   = nsp[0];
    const int tid  = threadIdx.x;
    const int lane = tid & 63;
    const int wave = tid >> 6;
    const int il   = lane & 15;
    const int quad = lane >> 4;
    const int bb   = blockIdx.x * 16;

    float* cal = out + (size_t)B * ns * 8;
    float* res = cal + ns;

    if (blockIdx.x == 0)
        for (int t = tid; t < ns; t += 256) cal[t] = t * DTC;

    for (int i = tid; i < 16 * U1S; i += 256) U1[i] = 0;

    // ---- register-resident B-fragments (constant over time) ----
    // Wave w owns gate columns n = 64*j + 16*w + il for j = i,f,g,o, so each
    // wave's MFMA output holds complete (i,f,g,o) quadruples for hidden
    // indices [16w,16w+16) -> cell update entirely in registers.
    // Gate pre-scale folded into bf16 weights: gamma = -1/ln2 for sigmoid
    // gates (i,f,o), +2/ln2 for g (tanh). Cell state c is carried LAM-scaled.
    //
    // s is removed from the MFMA path: gs[j] carries gamma*(b0 + W_x*x + W_s*s(t))
    // in fp32 registers, updated incrementally each step via
    //   gs += MFMA(h_b(t-1), gamma*DT*(W_s@fc_W)) + gamma*DT*(W_s@fc_b)
    // which is exact (s recurrence is affine in h_b).
    short8 B0[4][2], B1[4][4], M2f[4][2], BF[2];
    floatx4 gs[4], bias1v[4];
    float gd[4];

    for (int j = 0; j < 4; ++j) {
        const float gam = (j == 2) ? LAM : -L2E;
        const int n = 64 * j + 16 * wave + il;
        float ws[8];                           // W_s row n (s-columns of W_ih0)
        #pragma unroll
        for (int p = 0; p < 8; ++p) ws[p] = W_ih0[n * 16 + 8 + p];

        #pragma unroll
        for (int kk = 0; kk < 2; ++kk) {       // G0: K = h_a(64)
            short8 f;
            #pragma unroll
            for (int jj = 0; jj < 8; ++jj) {
                int k = 32 * kk + 8 * quad + jj;
                f[jj] = (short)f2bf(gam * W_hh0[n * 64 + k]);
            }
            B0[j][kk] = f;
        }
        #pragma unroll
        for (int kk = 0; kk < 4; ++kk) {       // G1: K = [h_a(64) | h_b(64)]
            short8 f;
            #pragma unroll
            for (int jj = 0; jj < 8; ++jj) {
                int k = 32 * kk + 8 * quad + jj;
                float w = (k < 64) ? W_ih1[n * 64 + k] : W_hh1[n * 64 + (k - 64)];
                f[jj] = (short)f2bf(gam * w);
            }
            B1[j][kk] = f;
        }
        #pragma unroll
        for (int kk = 0; kk < 2; ++kk) {       // M2[n][k] = sum_p W_s[n][p]*fc_W[p][k]
            short8 f;
            #pragma unroll
            for (int jj = 0; jj < 8; ++jj) {
                int k = 32 * kk + 8 * quad + jj;
                float acc = 0.0f;
                #pragma unroll
                for (int p = 0; p < 8; ++p) acc += ws[p] * fc_W[p * 64 + k];
                f[jj] = (short)f2bf(gam * DTC * acc);
            }
            M2f[j][kk] = f;
        }
        float accb = 0.0f;
        #pragma unroll
        for (int p = 0; p < 8; ++p) accb += ws[p] * fc_b[p];
        gd[j] = gam * DTC * accb;

        float bcol = b_ih0[n] + b_hh0[n];
        floatx4 gv;
        #pragma unroll
        for (int reg = 0; reg < 4; ++reg) {
            int m = 4 * quad + reg;
            float acc = bcol;
            #pragma unroll
            for (int k = 0; k < 8; ++k) acc += x[(bb + m) * 8 + k] * W_ih0[n * 16 + k];
            #pragma unroll
            for (int p = 0; p < 8; ++p) acc += ws[p] * s0[(bb + m) * 8 + p];
            // pre-subtract gd: the (unconditional) t=0 gs-update adds it back
            gv[reg] = gam * acc - gd[j];
        }
        gs[j] = gv;
        float b1 = gam * (b_ih1[n] + b_hh1[n]);
        bias1v[j] = (floatx4){b1, b1, b1, b1};
    }
    #pragma unroll
    for (int kk = 0; kk < 2; ++kk) {           // FC head (unscaled, exact output path)
        short8 f;
        #pragma unroll
        for (int jj = 0; jj < 8; ++jj) {
            int k = 32 * kk + 8 * quad + jj;
            float w = (il < 8) ? fc_W[il * 64 + k] : 0.0f;
            f[jj] = (short)f2bf(w);
        }
        BF[kk] = f;
    }
    const float fcb = (il < 8) ? fc_b[il] : 0.0f;

    // ---- state ----
    float cA[4] = {0, 0, 0, 0}, cB[4] = {0, 0, 0, 0};   // LAM-scaled cell states
    float s_reg[4];
    #pragma unroll
    for (int reg = 0; reg < 4; ++reg) {
        int m = 4 * quad + reg;
        s_reg[reg] = (il < 8) ? s0[(bb + m) * 8 + il] : 0.0f;
    }

    short8 a10 = {0, 0, 0, 0, 0, 0, 0, 0};     // h_a(t-1) frags carried in registers
    short8 a11 = {0, 0, 0, 0, 0, 0, 0, 0};
    const int iidx = 16 * wave + il;
    wg_barrier();

    // Per-step barrier safety with only TWO barriers:
    //  - cell0 writes cols 0..63: the only LDS readers of 0..63 are the
    //    a10/a11 reads after barrier B, consumed (lgkm-waited) before barrier
    //    C of the same step -> after C no pending reads; next step may write.
    //  - cell1 writes cols 64..127 (after B): a12/a13 reads of 64..127 are
    //    consumed by the p1 MFMAs before B in every wave -> safe.
    //  - h_b(t) write -> next step's a12/a13 read: ordered by barrier C.
    #pragma unroll 1
    for (int t = 0; t < ns; ++t) {
        // ---- phase 1 ----
        short8 a12 = *(const short8*)&U1[il * U1S + 64 + 8 * quad];  // h_b(t-1)
        short8 a13 = *(const short8*)&U1[il * U1S + 96 + 8 * quad];

        floatx4 g0[4];
        #pragma unroll
        for (int j = 0; j < 4; ++j) {          // h_a part: registers only, no LDS wait
            floatx4 z = {0.f, 0.f, 0.f, 0.f};
            z = MFMA(a10, B0[j][0], z);
            z = MFMA(a11, B0[j][1], z);
            g0[j] = z;
        }
        #pragma unroll
        for (int j = 0; j < 4; ++j) {          // gs(t) = gs(t-1) + gamma*W_s*(DT*step_out(t-1))
            floatx4 z = gs[j];
            z = MFMA(a12, M2f[j][0], z);
            z = MFMA(a13, M2f[j][1], z);
            #pragma unroll
            for (int reg = 0; reg < 4; ++reg) z[reg] += gd[j];
            gs[j] = z;
        }
        floatx4 p1[4];
        #pragma unroll
        for (int j = 0; j < 4; ++j) {          // layer-1 h_b partial (hides under cell0)
            floatx4 z = bias1v[j];
            z = MFMA(a12, B1[j][2], z);
            z = MFMA(a13, B1[j][3], z);
            p1[j] = z;
        }
        #pragma unroll
        for (int reg = 0; reg < 4; ++reg) {    // cell 0 (pre-scaled gates)
            float iv = rcp1p(g0[0][reg] + gs[0][reg]);
            float fv = rcp1p(g0[1][reg] + gs[1][reg]);
            float gr = rcp1p(g0[2][reg] + gs[2][reg]);
            float gl = __builtin_fmaf(gr, -2.0f * LAM, LAM);   // LAM*tanh(g)
            float ov = rcp1p(g0[3][reg] + gs[3][reg]);
            float c  = __builtin_fmaf(fv, cA[reg], iv * gl);   // LAM-scaled c
            cA[reg]  = c;
            float r2 = rcp1p(c);                               // tanh(c) = 1-2*r2
            float u  = ov * r2;
            float h  = __builtin_fmaf(-2.0f, u, ov);
            U1[(4 * quad + reg) * U1S + iidx] = f2bf(h);       // h_a(t)
        }
        wg_barrier();   // B

        // ---- phase 2 ----
        a10 = *(const short8*)&U1[il * U1S + 0  + 8 * quad];   // h_a(t), reused next iter
        a11 = *(const short8*)&U1[il * U1S + 32 + 8 * quad];

        if (t && wave == 0) {                  // deferred FC(t-1): fills the read bubble
            floatx4 so = {fcb, fcb, fcb, fcb};
            so = MFMA(a12, BF[0], so);
            so = MFMA(a13, BF[1], so);
            #pragma unroll
            for (int reg = 0; reg < 4; ++reg) {
                s_reg[reg] += so[reg] * DTC;
                if (il < 8) {
                    int m = 4 * quad + reg;
                    size_t o = ((size_t)(bb + m) * ns + (t - 1)) * 8 + il;
                    out[o] = s_reg[reg];
                    res[o] = so[reg];
                }
            }
        }

        floatx4 g1[4];
        #pragma unroll
        for (int j = 0; j < 4; ++j) {
            floatx4 z = p1[j];
            z = MFMA(a10, B1[j][0], z);
            z = MFMA(a11, B1[j][1], z);
            g1[j] = z;
        }
        #pragma unroll
        for (int reg = 0; reg < 4; ++reg) {    // cell 1
            float iv = rcp1p(g1[0][reg]);
            float fv = rcp1p(g1[1][reg]);
            float gr = rcp1p(g1[2][reg]);
            float gl = __builtin_fmaf(gr, -2.0f * LAM, LAM);
            float ov = rcp1p(g1[3][reg]);
            float c  = __builtin_fmaf(fv, cB[reg], iv * gl);
            cB[reg]  = c;
            float r2 = rcp1p(c);
            float u  = ov * r2;
            float h  = __builtin_fmaf(-2.0f, u, ov);
            U1[(4 * quad + reg) * U1S + 64 + iidx] = f2bf(h);  // h_b(t)
        }
        wg_barrier();   // C
    }

    // epilogue: deferred FC for the final step (h_b(ns-1) visible after last C)
    if (wave == 0) {
        short8 a12 = *(const short8*)&U1[il * U1S + 64 + 8 * quad];
        short8 a13 = *(const short8*)&U1[il * U1S + 96 + 8 * quad];
        floatx4 so = {fcb, fcb, fcb, fcb};
        so = MFMA(a12, BF[0], so);
        so = MFMA(a13, BF[1], so);
        #pragma unroll
        for (int reg = 0; reg < 4; ++reg) {
            s_reg[reg] += so[reg] * DTC;
            if (il < 8) {
                int m = 4 * quad + reg;
                size_t o = ((size_t)(bb + m) * ns + (ns - 1)) * 8 + il;
                out[o] = s_reg[reg];
                res[o] = so[reg];
            }
        }
    }
}

extern "C" void kernel_launch(void* const* d_in, const int* in_sizes, int n_in,
                              void* d_out, int out_size, void* d_ws, size_t ws_size,
                              hipStream_t stream) {
    const float* x     = (const float*)d_in[0];
    const float* s0    = (const float*)d_in[1];
    const float* W_ih0 = (const float*)d_in[2];
    const float* W_hh0 = (const float*)d_in[3];
    const float* b_ih0 = (const float*)d_in[4];
    const float* b_hh0 = (const float*)d_in[5];
    const float* W_ih1 = (const float*)d_in[6];
    const float* W_hh1 = (const float*)d_in[7];
    const float* b_ih1 = (const float*)d_in[8];
    const float* b_hh1 = (const float*)d_in[9];
    const float* fc_W  = (const float*)d_in[10];
    const float* fc_b  = (const float*)d_in[11];
    const int*   nsp   = (const int*)d_in[12];
    (void)d_ws; (void)ws_size; (void)n_in; (void)out_size;
    int B = in_sizes[0] / 8;          // 4096
    dim3 grid(B / 16), block(256);    // 256 blocks -> 1 per CU
    hipLaunchKernelGGL(lstm_mfma, grid, block, 0, stream,
        x, s0, W_ih0, W_hh0, b_ih0, b_hh0, W_ih1, W_hh1, b_ih1, b_hh1,
        fc_W, fc_b, nsp, (float*)d_out, B);
}